// Round 13
// baseline (143.992 us; speedup 1.0000x reference)
//
#include <hip/hip_runtime.h>
#include <hip/hip_bf16.h>
#include <math.h>

#define N_TOK 4096
#define IN_CH 256
#define OUT_CH 64
#define HEADS 8
#define PROJ (OUT_CH * HEADS) /* 512 */
#define NLOG2E -1.44269504088896340736f

typedef float f32x4 __attribute__((ext_vector_type(4)));
typedef float f32x16 __attribute__((ext_vector_type(16)));
typedef __bf16 bf16x8 __attribute__((ext_vector_type(8)));
typedef unsigned short ushort_t;
typedef _Float16 f16_t;

__device__ inline ushort_t bf16rne(float x) {
    unsigned u = __float_as_uint(x);
    unsigned r = (u + 0x7FFFu + ((u >> 16) & 1u)) >> 16;
    return (ushort_t)r;
}

// packed f32->bf16x2 convert (RNE): D[15:0]=bf16(lo), D[31:16]=bf16(hi).
__device__ inline unsigned cvtpk_bf16(float lo, float hi) {
    unsigned d;
    asm("v_cvt_pk_bf16_f32 %0, %1, %2" : "=v"(d) : "v"(lo), "v"(hi));
    return d;
}
// v_permlane32_swap_b32 VDST, VSRC (R5-verified semantics):
// After PLSWAP(x, y):  x = {lo: own x,      hi: partner y}
//                      y = {lo: partner x,  hi: own y}
#define PLSWAP(x, y) asm("v_permlane32_swap_b32 %0, %1" : "+v"(x), "+v"(y))

// NOTE: the SIGPK fused-softmax macro remains RETIRED (R8/R9 bit-identical
// miscompile at absmax 860.033; R10 isolated it).  Softmax stays in the
// p[16] form below.

// async global->LDS DMA, 16B per lane.  LDS dest = wave-uniform base +
// lane*16; swizzle achieved by pre-swizzling the per-lane GLOBAL address.
__device__ inline void gld_lds16(const ushort_t* g, ushort_t* l) {
    __builtin_amdgcn_global_load_lds(
        (const __attribute__((address_space(1))) unsigned int*)g,
        (__attribute__((address_space(3))) unsigned int*)l,
        16, 0, 0);
}

// ---------------------------------------------------------------------------
// Kernel 1 (R13): Q/K/V projections with FUSED f32->bf16 cast.
// The separate cast_pack kernel is deleted; proj reads X / W as f32 and
// converts in-register using the SAME bf16rne + (-log2e on Wq) as cast did,
// with the cast_pack fragment mappings inlined per-lane -> MFMA inputs are
// bit-identical to R12's.
// Structure change: the whole W tile (64 cols x 256 ch bf16 = 32 KB) is
// staged ONCE (own-fragment mapping: lane (w,quad,l15) loads
// W[(c0+w*16+l15)][k8*32+quad*8..+7], writes Ws[k8*2048 + w*512 + lane*8]),
// then ONE barrier, then all 32 MFMAs back-to-back (replaces R12's 8
// barrier-drained k8 iterations).  X frags are per-wave private f32 loads
// converted just-in-time (no barrier needed; compiler pipelines).
// Es (epilogue transpose tile) ALIASES Ws -- guarded by a barrier after the
// last MFMA read of Ws.  LDS = 32 KB.
// grid (PROJ/64, N/64, 3), block 256 (4 waves).
//   z=0 -> Qb [N][PROJ] (pre-scaled by -log2e), z=1 -> Kb, z=2 -> Vt [H][64][N]
// ---------------------------------------------------------------------------
__global__ __launch_bounds__(256) void proj_mfma_kernel(
    const float* __restrict__ X,
    const float* __restrict__ Wq, const float* __restrict__ Wk,
    const float* __restrict__ Wv,
    const float* __restrict__ bq, const float* __restrict__ bk,
    const float* __restrict__ bv,
    ushort_t* __restrict__ Qb, ushort_t* __restrict__ Kb,
    ushort_t* __restrict__ Vt)
{
    const int z = blockIdx.z;
    const float* W    = (z == 0) ? Wq : (z == 1) ? Wk : Wv;
    const float* bias = (z == 0) ? bq : (z == 1) ? bk : bv;
    const float wscale = (z == 0) ? NLOG2E : 1.0f;
    const float bscale = (z == 0) ? NLOG2E : 1.0f;
    const int c0 = blockIdx.x * 64;
    const int n0 = blockIdx.y * 64;

    const int tid = threadIdx.x;
    const int w = tid >> 6;
    const int lane = tid & 63;
    const int l15 = lane & 15;
    const int quad = lane >> 4;

    __shared__ ushort_t Ws[8 * 2048];  // 32 KB: [k8][colgroup f][lane*8] bf16
    ushort_t* Es = Ws;                 // epilogue transpose tile aliases Ws

    // ---- stage W tile (own-fragment mapping; applies wscale) ----
    {
        const float* wsrc = W + (size_t)(c0 + w * 16 + l15) * IN_CH + quad * 8;
#pragma unroll
        for (int k8 = 0; k8 < 8; ++k8) {
            float4 a = *(const float4*)(wsrc + k8 * 32);
            float4 b = *(const float4*)(wsrc + k8 * 32 + 4);
            ushort_t pk[8];
            pk[0] = bf16rne(a.x * wscale); pk[1] = bf16rne(a.y * wscale);
            pk[2] = bf16rne(a.z * wscale); pk[3] = bf16rne(a.w * wscale);
            pk[4] = bf16rne(b.x * wscale); pk[5] = bf16rne(b.y * wscale);
            pk[6] = bf16rne(b.z * wscale); pk[7] = bf16rne(b.w * wscale);
            *(uint4*)&Ws[k8 * 2048 + w * 512 + lane * 8] = *(uint4*)pk;
        }
    }
    __syncthreads();                   // W tile visible to all waves

    f32x4 acc[4] = {{0.f, 0.f, 0.f, 0.f}, {0.f, 0.f, 0.f, 0.f},
                    {0.f, 0.f, 0.f, 0.f}, {0.f, 0.f, 0.f, 0.f}};

    const float* xsrc = X + (size_t)(n0 + w * 16 + l15) * IN_CH + quad * 8;
#pragma unroll
    for (int k8 = 0; k8 < 8; ++k8) {
        float4 xa = *(const float4*)(xsrc + k8 * 32);
        float4 xb = *(const float4*)(xsrc + k8 * 32 + 4);
        union { ushort_t u[8]; bf16x8 v; } ax;
        ax.u[0] = bf16rne(xa.x); ax.u[1] = bf16rne(xa.y);
        ax.u[2] = bf16rne(xa.z); ax.u[3] = bf16rne(xa.w);
        ax.u[4] = bf16rne(xb.x); ax.u[5] = bf16rne(xb.y);
        ax.u[6] = bf16rne(xb.z); ax.u[7] = bf16rne(xb.w);
#pragma unroll
        for (int f = 0; f < 4; ++f) {
            bf16x8 b = *(const bf16x8*)&Ws[k8 * 2048 + f * 512 + lane * 8];
            acc[f] = __builtin_amdgcn_mfma_f32_16x16x32_bf16(ax.v, b, acc[f], 0, 0, 0);
        }
    }
    __syncthreads();                   // all Ws reads done before Es overwrite

    // bias + bf16 round into LDS (layout depends on z), then coalesced store
    if (z < 2) {
        // Es[tok][c]
#pragma unroll
        for (int f = 0; f < 4; ++f) {
            const float bb = bias[c0 + f * 16 + l15] * bscale;
#pragma unroll
            for (int r = 0; r < 4; ++r)
                Es[(w * 16 + quad * 4 + r) * 68 + f * 16 + l15] = bf16rne(acc[f][r] + bb);
        }
    } else {
        // Es[c][tok]
#pragma unroll
        for (int f = 0; f < 4; ++f) {
            const float bb = bias[c0 + f * 16 + l15];
#pragma unroll
            for (int r = 0; r < 4; ++r)
                Es[(f * 16 + l15) * 68 + w * 16 + quad * 4 + r] = bf16rne(acc[f][r] + bb);
        }
    }
    __syncthreads();

    const int erow = tid >> 2;            // 0..63
    const int ecol = (tid & 3) * 16;      // 0,16,32,48 (+8 second store)
    uint4 pk0 = *(uint4*)&Es[erow * 68 + ecol];
    uint4 pk1 = *(uint4*)&Es[erow * 68 + ecol + 8];
    if (z < 2) {
        ushort_t* out = z ? Kb : Qb;
        ushort_t* p = &out[(size_t)(n0 + erow) * PROJ + c0 + ecol];
        *(uint4*)p = pk0;
        *(uint4*)(p + 8) = pk1;
    } else {
        ushort_t* p = &Vt[(size_t)(c0 + erow) * N_TOK + n0 + ecol];
        *(uint4*)p = pk0;
        *(uint4*)(p + 8) = pk1;
    }
}

// ---------------------------------------------------------------------------
// Kernel 2 (R12-proven, byte-identical): fused sigmoid attention,
// bf16 MFMA 32x32x16.  global_load_lds K/V staging, double-buffered, one
// barrier/tile; Ps-LDS-free softmax (T12 cvt_pk + permlane32_swap); 32-key
// half-pipelines with p[16] softmax; DEN on the MFMA pipe via ones-B
// fragment (dacc in AGPRs); NUM stored f16.
// block 256 (4 waves x 32 q), grid (32, 8, ZS=4) = 1024 = 4/CU.
// ---------------------------------------------------------------------------
template<int ZS>
__global__ __launch_bounds__(256, 4) void attn_kernel(
    const ushort_t* __restrict__ Qb, const ushort_t* __restrict__ Kb,
    const ushort_t* __restrict__ Vt,
    f16_t* __restrict__ NUM, float* __restrict__ DEN)
{
    constexpr int KEYS = N_TOK / ZS;      // keys per block
    constexpr int TILES = KEYS / 64;      // 64-key tiles per block

    const int h = blockIdx.y;
    const int z = blockIdx.z;
    const int n0 = blockIdx.x * 128;
    const int tid = threadIdx.x;
    const int w = tid >> 6;               // 0..3, wave owns queries w*32..+31
    const int lane = tid & 63;
    const int l31 = lane & 31;
    const int hf = lane >> 5;             // half-wave: k-chunk select

    __shared__ ushort_t Ks[2 * 64 * 64];  // [buf][key][d], xor-swizzled chunks
    __shared__ ushort_t Vs[2 * 64 * 64];  // [buf][d][key], xor-swizzled chunks

    // Q B-fragments, register-resident (pre-scaled by -log2e).
    bf16x8 qb[4];
    {
        const ushort_t* base = Qb + (size_t)(n0 + w * 32 + l31) * PROJ + h * 64 + hf * 8;
        qb[0] = *(const bf16x8*)(base);
        qb[1] = *(const bf16x8*)(base + 16);
        qb[2] = *(const bf16x8*)(base + 32);
        qb[3] = *(const bf16x8*)(base + 48);
    }

    bf16x8 onesv;
#pragma unroll
    for (int j = 0; j < 8; ++j) onesv[j] = (__bf16)1.0f;

    f32x16 o0 = {};                       // O[q][d: 0..31]
    f32x16 o1 = {};                       // O[q][d: 32..63]
    f32x16 dacc = {};                     // DEN via MFMA-ones (R0-R2 proven)

    // DMA staging geometry: wave w covers rows w*16..w*16+15 in two issues
    // of 8 rows; lane -> (row = r0 + (lane>>3), physical chunk = lane&7).
    // Global source fetches logical chunk pc ^ (row&7) = pc ^ lrow.
    const int lrow = lane >> 3;
    const int pc = lane & 7;
    const int swz = (pc ^ lrow) * 8;      // shorts
    const int lb = w * 1024;              // wave's LDS base (shorts)
    const ushort_t* kg = Kb + (size_t)h * 64 +
                         ((size_t)z * KEYS + w * 16 + lrow) * PROJ + swz;
    const ushort_t* vg = Vt + ((size_t)h * 64 + w * 16 + lrow) * N_TOK +
                         (size_t)z * KEYS + swz;

    const int xm = l31 & 7;               // fragment-read swizzle mask

    // prologue: stage tile 0 -> buf 0 (drained by first loop barrier)
    gld_lds16(kg,             &Ks[lb]);
    gld_lds16(kg + 8 * PROJ,  &Ks[lb + 512]);
    gld_lds16(vg,             &Vs[lb]);
    gld_lds16(vg + 8 * N_TOK, &Vs[lb + 512]);
    kg += 64 * PROJ;
    vg += 64;

    for (int lt = 0; lt < TILES; ++lt) {
        const int bo = (lt & 1) << 12;    // read-buffer offset (shorts)
        __syncthreads();                  // vmcnt(0)+barrier: buf[lt&1] ready,
                                          // all waves done with buf[lt^1]
        if (lt + 1 < TILES) {             // DMA tile lt+1 into other buffer
            const int bw = ((lt + 1) & 1) << 12;
            gld_lds16(kg,             &Ks[bw + lb]);
            gld_lds16(kg + 8 * PROJ,  &Ks[bw + lb + 512]);
            gld_lds16(vg,             &Vs[bw + lb]);
            gld_lds16(vg + 8 * N_TOK, &Vs[bw + lb + 512]);
            kg += 64 * PROJ;
            vg += 64;
        }

        // ================= half A: keys 0-31 =================
        {
            f32x16 s0 = {};
            __builtin_amdgcn_s_setprio(1);
#pragma unroll
            for (int ks = 0; ks < 4; ++ks) {
                const int pos = ((ks * 2 + hf) ^ xm) * 8;
                bf16x8 ka = *(const bf16x8*)&Ks[bo + l31 * 64 + pos];
                s0 = __builtin_amdgcn_mfma_f32_32x32x16_bf16(ka, qb[ks], s0, 0, 0, 0);
            }
            __builtin_amdgcn_s_setprio(0);

            float p[16];
#pragma unroll
            for (int r = 0; r < 16; ++r) {
                p[r] = __builtin_amdgcn_rcpf(1.0f + __builtin_amdgcn_exp2f(s0[r]));
            }
            unsigned d00 = cvtpk_bf16(p[0],  p[1]);
            unsigned d01 = cvtpk_bf16(p[2],  p[3]);
            unsigned d10 = cvtpk_bf16(p[4],  p[5]);
            unsigned d11 = cvtpk_bf16(p[6],  p[7]);
            unsigned d20 = cvtpk_bf16(p[8],  p[9]);
            unsigned d21 = cvtpk_bf16(p[10], p[11]);
            unsigned d30 = cvtpk_bf16(p[12], p[13]);
            unsigned d31 = cvtpk_bf16(p[14], p[15]);
            PLSWAP(d00, d10);
            PLSWAP(d01, d11);
            PLSWAP(d20, d30);
            PLSWAP(d21, d31);
            union { unsigned u[4]; bf16x8 v; } A0, A1;
            A0.u[0] = d00; A0.u[1] = d01; A0.u[2] = d10; A0.u[3] = d11;
            A1.u[0] = d20; A1.u[1] = d21; A1.u[2] = d30; A1.u[3] = d31;

            __builtin_amdgcn_s_setprio(1);
            {
                const int pos = ((0 + hf) ^ xm) * 8;          // ks=0
                bf16x8 vb0 = *(const bf16x8*)&Vs[bo + l31 * 64 + pos];
                o0 = __builtin_amdgcn_mfma_f32_32x32x16_bf16(A0.v, vb0, o0, 0, 0, 0);
                bf16x8 vb1 = *(const bf16x8*)&Vs[bo + (32 + l31) * 64 + pos];
                o1 = __builtin_amdgcn_mfma_f32_32x32x16_bf16(A0.v, vb1, o1, 0, 0, 0);
            }
            dacc = __builtin_amdgcn_mfma_f32_32x32x16_bf16(A0.v, onesv, dacc, 0, 0, 0);
            {
                const int pos = ((2 + hf) ^ xm) * 8;          // ks=1
                bf16x8 vb0 = *(const bf16x8*)&Vs[bo + l31 * 64 + pos];
                o0 = __builtin_amdgcn_mfma_f32_32x32x16_bf16(A1.v, vb0, o0, 0, 0, 0);
                bf16x8 vb1 = *(const bf16x8*)&Vs[bo + (32 + l31) * 64 + pos];
                o1 = __builtin_amdgcn_mfma_f32_32x32x16_bf16(A1.v, vb1, o1, 0, 0, 0);
            }
            dacc = __builtin_amdgcn_mfma_f32_32x32x16_bf16(A1.v, onesv, dacc, 0, 0, 0);
            __builtin_amdgcn_s_setprio(0);
        }

        // ================= half B: keys 32-63 =================
        {
            f32x16 s1 = {};
            __builtin_amdgcn_s_setprio(1);
#pragma unroll
            for (int ks = 0; ks < 4; ++ks) {
                const int pos = ((ks * 2 + hf) ^ xm) * 8;
                bf16x8 ka = *(const bf16x8*)&Ks[bo + (32 + l31) * 64 + pos];
                s1 = __builtin_amdgcn_mfma_f32_32x32x16_bf16(ka, qb[ks], s1, 0, 0, 0);
            }
            __builtin_amdgcn_s_setprio(0);

            float p[16];
#pragma unroll
            for (int r = 0; r < 16; ++r) {
                p[r] = __builtin_amdgcn_rcpf(1.0f + __builtin_amdgcn_exp2f(s1[r]));
            }
            unsigned e00 = cvtpk_bf16(p[0],  p[1]);
            unsigned e01 = cvtpk_bf16(p[2],  p[3]);
            unsigned e10 = cvtpk_bf16(p[4],  p[5]);
            unsigned e11 = cvtpk_bf16(p[6],  p[7]);
            unsigned e20 = cvtpk_bf16(p[8],  p[9]);
            unsigned e21 = cvtpk_bf16(p[10], p[11]);
            unsigned e30 = cvtpk_bf16(p[12], p[13]);
            unsigned e31 = cvtpk_bf16(p[14], p[15]);
            PLSWAP(e00, e10);
            PLSWAP(e01, e11);
            PLSWAP(e20, e30);
            PLSWAP(e21, e31);
            union { unsigned u[4]; bf16x8 v; } A2, A3;
            A2.u[0] = e00; A2.u[1] = e01; A2.u[2] = e10; A2.u[3] = e11;
            A3.u[0] = e20; A3.u[1] = e21; A3.u[2] = e30; A3.u[3] = e31;

            __builtin_amdgcn_s_setprio(1);
            {
                const int pos = ((4 + hf) ^ xm) * 8;          // ks=2
                bf16x8 vb0 = *(const bf16x8*)&Vs[bo + l31 * 64 + pos];
                o0 = __builtin_amdgcn_mfma_f32_32x32x16_bf16(A2.v, vb0, o0, 0, 0, 0);
                bf16x8 vb1 = *(const bf16x8*)&Vs[bo + (32 + l31) * 64 + pos];
                o1 = __builtin_amdgcn_mfma_f32_32x32x16_bf16(A2.v, vb1, o1, 0, 0, 0);
            }
            dacc = __builtin_amdgcn_mfma_f32_32x32x16_bf16(A2.v, onesv, dacc, 0, 0, 0);
            {
                const int pos = ((6 + hf) ^ xm) * 8;          // ks=3
                bf16x8 vb0 = *(const bf16x8*)&Vs[bo + l31 * 64 + pos];
                o0 = __builtin_amdgcn_mfma_f32_32x32x16_bf16(A3.v, vb0, o0, 0, 0, 0);
                bf16x8 vb1 = *(const bf16x8*)&Vs[bo + (32 + l31) * 64 + pos];
                o1 = __builtin_amdgcn_mfma_f32_32x32x16_bf16(A3.v, vb1, o1, 0, 0, 0);
            }
            dacc = __builtin_amdgcn_mfma_f32_32x32x16_bf16(A3.v, onesv, dacc, 0, 0, 0);
            __builtin_amdgcn_s_setprio(0);
        }
    }

    // epilogue: unnormalized numerator (f16).  q-row = (r&3)+8*(r>>2)+4*hf
#pragma unroll
    for (int rq = 0; rq < 4; ++rq) {
#pragma unroll
        for (int j = 0; j < 4; ++j) {
            const int q = n0 + w * 32 + rq * 8 + hf * 4 + j;
            f16_t* np_ = &NUM[((size_t)z * N_TOK + q) * PROJ + h * 64 + l31];
            np_[0]  = (f16_t)o0[rq * 4 + j];
            np_[32] = (f16_t)o1[rq * 4 + j];
        }
    }
    // DEN from dacc: D[q][c] = sum_k P[q][k]*1, identical across cols c.
    // Lane col l31==0 of each half writes its 16 q-rows.
    if (l31 == 0) {
#pragma unroll
        for (int r = 0; r < 16; ++r) {
            const int q = n0 + w * 32 + (r & 3) + 8 * (r >> 2) + 4 * hf;
            DEN[((size_t)z * N_TOK + q) * HEADS + h] = dacc[r];
        }
    }
}

// ---------------------------------------------------------------------------
// Kernel 3: out[n][d] = (1/8) * sum_h (sum_z NUM_z)/(sum_z DEN_z)
// NUM is f16; DEN stays f32.
// ---------------------------------------------------------------------------
template<int ZS>
__global__ __launch_bounds__(256) void reduce_kernel(
    const f16_t* __restrict__ NUM, const float* __restrict__ DEN,
    float* __restrict__ out)
{
    const int g = blockIdx.x * 256 + threadIdx.x;
    const int n = g >> 6;
    const int d = g & 63;
    float acc = 0.0f;
#pragma unroll
    for (int hh = 0; hh < HEADS; ++hh) {
        float num = 0.0f, dd = 0.0f;
#pragma unroll
        for (int zz = 0; zz < ZS; ++zz) {
            num += (float)NUM[((size_t)zz * N_TOK + n) * PROJ + hh * 64 + d];
            dd  += DEN[((size_t)zz * N_TOK + n) * HEADS + hh];
        }
        acc += num / dd;
    }
    out[g] = acc * 0.125f;
}

extern "C" void kernel_launch(void* const* d_in, const int* in_sizes, int n_in,
                              void* d_out, int out_size, void* d_ws, size_t ws_size,
                              hipStream_t stream) {
    (void)in_sizes; (void)n_in; (void)out_size;
    const float* X  = (const float*)d_in[0];
    const float* Wq = (const float*)d_in[1];
    const float* bq = (const float*)d_in[2];
    const float* Wk = (const float*)d_in[3];
    const float* bk = (const float*)d_in[4];
    const float* Wv = (const float*)d_in[5];
    const float* bv = (const float*)d_in[6];
    float* out = (float*)d_out;

    // ws need at ZS=4: 16.78M (NUM f16) + 0.52M (DEN) + 12.58M (Qb/Kb/Vt)
    //                = 29.9 MB (Xa/Wp eliminated in R13).  Fallback ZS=2.
    const size_t NEED4 =
        (size_t)4 * N_TOK * PROJ * 2 + (size_t)4 * N_TOK * HEADS * 4 +
        (size_t)3 * N_TOK * PROJ * 2;
    const int ZS = (ws_size >= NEED4) ? 4 : 2;

    f16_t* NUM = (f16_t*)d_ws;                              // [ZS][N][PROJ] f16
    float* DEN = (float*)(NUM + (size_t)ZS * N_TOK * PROJ); // [ZS][N][HEADS] f32
    ushort_t* Qb = (ushort_t*)(DEN + (size_t)ZS * N_TOK * HEADS);
    ushort_t* Kb = Qb + (size_t)N_TOK * PROJ;
    ushort_t* Vt = Kb + (size_t)N_TOK * PROJ;               // [H][64][N]

    proj_mfma_kernel<<<dim3(PROJ / 64, N_TOK / 64, 3), 256, 0, stream>>>(
        X, Wq, Wk, Wv, bq, bk, bv, Qb, Kb, Vt);
    if (ZS == 4) {
        attn_kernel<4><<<dim3(N_TOK / 128, HEADS, 4), 256, 0, stream>>>(
            Qb, Kb, Vt, NUM, DEN);
        reduce_kernel<4><<<dim3(N_TOK * OUT_CH / 256), 256, 0, stream>>>(
            NUM, DEN, out);
    } else {
        attn_kernel<2><<<dim3(N_TOK / 128, HEADS, 2), 256, 0, stream>>>(
            Qb, Kb, Vt, NUM, DEN);
        reduce_kernel<2><<<dim3(N_TOK * OUT_CH / 256), 256, 0, stream>>>(
            NUM, DEN, out);
    }
}

// Round 14
// 133.364 us; speedup vs baseline: 1.0797x; 1.0797x over previous
//
#include <hip/hip_runtime.h>
#include <hip/hip_bf16.h>
#include <math.h>

#define N_TOK 4096
#define IN_CH 256
#define OUT_CH 64
#define HEADS 8
#define PROJ (OUT_CH * HEADS) /* 512 */
#define NLOG2E -1.44269504088896340736f

typedef float f32x4 __attribute__((ext_vector_type(4)));
typedef float f32x16 __attribute__((ext_vector_type(16)));
typedef __bf16 bf16x8 __attribute__((ext_vector_type(8)));
typedef unsigned short ushort_t;
typedef _Float16 f16_t;

__device__ inline ushort_t bf16rne(float x) {
    unsigned u = __float_as_uint(x);
    unsigned r = (u + 0x7FFFu + ((u >> 16) & 1u)) >> 16;
    return (ushort_t)r;
}

// packed f32->bf16x2 convert (RNE): D[15:0]=bf16(lo), D[31:16]=bf16(hi).
__device__ inline unsigned cvtpk_bf16(float lo, float hi) {
    unsigned d;
    asm("v_cvt_pk_bf16_f32 %0, %1, %2" : "=v"(d) : "v"(lo), "v"(hi));
    return d;
}
// v_permlane32_swap_b32 VDST, VSRC (R5-verified semantics):
// After PLSWAP(x, y):  x = {lo: own x,      hi: partner y}
//                      y = {lo: partner x,  hi: own y}
#define PLSWAP(x, y) asm("v_permlane32_swap_b32 %0, %1" : "+v"(x), "+v"(y))

// NOTE: SIGPK fused-softmax macro remains RETIRED (R8/R9 miscompile).
// NOTE (R14): the R13 cast-into-proj fusion is RETIRED — it replaced the
// cast kernel's coalesced packed-bf16 reads with 16-row-strided f32 reads
// (2x bytes, scattered 128B segments) and regressed the bucket +16 us.
// The standalone cast kernel pays for itself.

// async global->LDS DMA, 16B per lane.  LDS dest = wave-uniform base +
// lane*16; swizzle achieved by pre-swizzling the per-lane GLOBAL address.
__device__ inline void gld_lds16(const ushort_t* g, ushort_t* l) {
    __builtin_amdgcn_global_load_lds(
        (const __attribute__((address_space(1))) unsigned int*)g,
        (__attribute__((address_space(3))) unsigned int*)l,
        16, 0, 0);
}

// ---------------------------------------------------------------------------
// Kernel 0: cast X / Wq / Wk / Wv to bf16 AND pre-permute into MFMA fragment
// order:  flat index (((g*8 + k8)*4 + quad)*16 + t)*8  (g = 16-row group).
// Wq additionally scaled by -log2(e) so sigmoid = rcp(1 + exp2(t)).
// ---------------------------------------------------------------------------
__global__ __launch_bounds__(256) void cast_pack_kernel(
    const float* __restrict__ X,
    const float* __restrict__ Wq, const float* __restrict__ Wk,
    const float* __restrict__ Wv,
    ushort_t* __restrict__ Xa, ushort_t* __restrict__ Wp)
{
    const int i = blockIdx.x * 256 + threadIdx.x;
    const float* src;
    ushort_t* dst;
    float scale = 1.0f;
    if (i < 131072) {                       // X part: N*IN_CH/8 packs
        const int t = i & 15, quad = (i >> 4) & 3, k8 = (i >> 6) & 7, g = i >> 9;
        src = X + (size_t)(g * 16 + t) * IN_CH + k8 * 32 + quad * 8;
        dst = Xa + (size_t)i * 8;
    } else {                                // W part: 3*PROJ*IN_CH/8 packs
        const int j = i - 131072;
        const int z = j >> 14;
        const int r = j & 16383;
        const int cl = r & 15, quad = (r >> 4) & 3, k8 = (r >> 6) & 7, gc = r >> 9;
        const float* W = (z == 0) ? Wq : (z == 1) ? Wk : Wv;
        src = W + (size_t)(gc * 16 + cl) * IN_CH + k8 * 32 + quad * 8;
        dst = Wp + (size_t)z * 131072 * 8 + (size_t)r * 8;
        if (z == 0) scale = NLOG2E;
    }
    float4 a = *(const float4*)src;
    float4 b = *(const float4*)(src + 4);
    ushort_t pk[8];
    pk[0] = bf16rne(a.x * scale); pk[1] = bf16rne(a.y * scale);
    pk[2] = bf16rne(a.z * scale); pk[3] = bf16rne(a.w * scale);
    pk[4] = bf16rne(b.x * scale); pk[5] = bf16rne(b.y * scale);
    pk[6] = bf16rne(b.z * scale); pk[7] = bf16rne(b.w * scale);
    *(uint4*)dst = *(uint4*)pk;
}

// ---------------------------------------------------------------------------
// Kernel 1 (R10-proven DMA version): Q/K/V projections via bf16 MFMA.
// grid (PROJ/64, N/64, 3), block 256 (4 waves).  Wave w: 16 tokens x 64 cols.
// W staged through LDS via global_load_lds DMA, double-buffered per
// k8-slice.  Global traffic/block: 160 -> 64 KB; b-operand L2 -> LDS.
// Epilogue: LDS transpose so all global stores are uint4.
//   z=0 -> Qb [N][PROJ] (pre-scaled by -log2e), z=1 -> Kb, z=2 -> Vt [H][64][N]
// ---------------------------------------------------------------------------
__global__ __launch_bounds__(256) void proj_mfma_kernel(
    const ushort_t* __restrict__ Xa, const ushort_t* __restrict__ Wp,
    const float* __restrict__ bq, const float* __restrict__ bk,
    const float* __restrict__ bv,
    ushort_t* __restrict__ Qb, ushort_t* __restrict__ Kb,
    ushort_t* __restrict__ Vt)
{
    const int z = blockIdx.z;
    const float* bias = (z == 0) ? bq : (z == 1) ? bk : bv;
    const float bscale = (z == 0) ? NLOG2E : 1.0f;
    const int c0 = blockIdx.x * 64;
    const int n0 = blockIdx.y * 64;

    const int tid = threadIdx.x;
    const int w = tid >> 6;
    const int lane = tid & 63;
    const int l15 = lane & 15;
    const int quad = lane >> 4;

    __shared__ ushort_t Ws[2 * 2048];  // [buf][colgroup f][lane*8] (8 KB)
    __shared__ ushort_t Es[64 * 68];   // epilogue transpose tile (8.7 KB)

    // X fragments: per-wave private, straight from global (L2-hot, read once)
    const ushort_t* xa = Xa + (size_t)(blockIdx.y * 4 + w) * 4096 + lane * 8;
    // W DMA source: wave w stages col-group w's k8-slice
    const ushort_t* wsrc = Wp + (size_t)z * 131072 * 8 +
                           (size_t)(blockIdx.x * 4 + w) * 4096 + lane * 8;

    f32x4 acc[4] = {{0.f, 0.f, 0.f, 0.f}, {0.f, 0.f, 0.f, 0.f},
                    {0.f, 0.f, 0.f, 0.f}, {0.f, 0.f, 0.f, 0.f}};

    // prologue: stage k8=0 slice -> buf0
    gld_lds16(wsrc, &Ws[w * 512]);

#pragma unroll
    for (int k8 = 0; k8 < 8; ++k8) {
        const int bo = (k8 & 1) * 2048;
        __syncthreads();               // vmcnt(0)+barrier: buf[k8&1] ready,
                                       // all waves done with buf[k8^1]
        if (k8 < 7)
            gld_lds16(wsrc + (k8 + 1) * 512,
                      &Ws[((k8 + 1) & 1) * 2048 + w * 512]);
        bf16x8 a = *(const bf16x8*)(xa + k8 * 512);
#pragma unroll
        for (int f = 0; f < 4; ++f) {
            bf16x8 b = *(const bf16x8*)&Ws[bo + f * 512 + lane * 8];
            acc[f] = __builtin_amdgcn_mfma_f32_16x16x32_bf16(a, b, acc[f], 0, 0, 0);
        }
    }

    // bias + bf16 round into LDS (layout depends on z), then coalesced store
    if (z < 2) {
        // Es[tok][c]
#pragma unroll
        for (int f = 0; f < 4; ++f) {
            const float bb = bias[c0 + f * 16 + l15] * bscale;
#pragma unroll
            for (int r = 0; r < 4; ++r)
                Es[(w * 16 + quad * 4 + r) * 68 + f * 16 + l15] = bf16rne(acc[f][r] + bb);
        }
    } else {
        // Es[c][tok]
#pragma unroll
        for (int f = 0; f < 4; ++f) {
            const float bb = bias[c0 + f * 16 + l15];
#pragma unroll
            for (int r = 0; r < 4; ++r)
                Es[(f * 16 + l15) * 68 + w * 16 + quad * 4 + r] = bf16rne(acc[f][r] + bb);
        }
    }
    __syncthreads();

    const int erow = tid >> 2;            // 0..63
    const int ecol = (tid & 3) * 16;      // 0,16,32,48 (+8 second store)
    uint4 pk0 = *(uint4*)&Es[erow * 68 + ecol];
    uint4 pk1 = *(uint4*)&Es[erow * 68 + ecol + 8];
    if (z < 2) {
        ushort_t* out = z ? Kb : Qb;
        ushort_t* p = &out[(size_t)(n0 + erow) * PROJ + c0 + ecol];
        *(uint4*)p = pk0;
        *(uint4*)(p + 8) = pk1;
    } else {
        ushort_t* p = &Vt[(size_t)(c0 + erow) * N_TOK + n0 + ecol];
        *(uint4*)p = pk0;
        *(uint4*)(p + 8) = pk1;
    }
}

// ---------------------------------------------------------------------------
// Kernel 2 (R12-proven, byte-identical): fused sigmoid attention,
// bf16 MFMA 32x32x16.  global_load_lds K/V staging, double-buffered, one
// barrier/tile; Ps-LDS-free softmax (T12 cvt_pk + permlane32_swap); 32-key
// half-pipelines with p[16] softmax; DEN on the MFMA pipe via ones-B
// fragment (dacc in AGPRs); NUM stored f16.
// block 256 (4 waves x 32 q), grid (32, 8, ZS=4) = 1024 = 4/CU.
// ---------------------------------------------------------------------------
template<int ZS>
__global__ __launch_bounds__(256, 4) void attn_kernel(
    const ushort_t* __restrict__ Qb, const ushort_t* __restrict__ Kb,
    const ushort_t* __restrict__ Vt,
    f16_t* __restrict__ NUM, float* __restrict__ DEN)
{
    constexpr int KEYS = N_TOK / ZS;      // keys per block
    constexpr int TILES = KEYS / 64;      // 64-key tiles per block

    const int h = blockIdx.y;
    const int z = blockIdx.z;
    const int n0 = blockIdx.x * 128;
    const int tid = threadIdx.x;
    const int w = tid >> 6;               // 0..3, wave owns queries w*32..+31
    const int lane = tid & 63;
    const int l31 = lane & 31;
    const int hf = lane >> 5;             // half-wave: k-chunk select

    __shared__ ushort_t Ks[2 * 64 * 64];  // [buf][key][d], xor-swizzled chunks
    __shared__ ushort_t Vs[2 * 64 * 64];  // [buf][d][key], xor-swizzled chunks

    // Q B-fragments, register-resident (pre-scaled by -log2e).
    bf16x8 qb[4];
    {
        const ushort_t* base = Qb + (size_t)(n0 + w * 32 + l31) * PROJ + h * 64 + hf * 8;
        qb[0] = *(const bf16x8*)(base);
        qb[1] = *(const bf16x8*)(base + 16);
        qb[2] = *(const bf16x8*)(base + 32);
        qb[3] = *(const bf16x8*)(base + 48);
    }

    bf16x8 onesv;
#pragma unroll
    for (int j = 0; j < 8; ++j) onesv[j] = (__bf16)1.0f;

    f32x16 o0 = {};                       // O[q][d: 0..31]
    f32x16 o1 = {};                       // O[q][d: 32..63]
    f32x16 dacc = {};                     // DEN via MFMA-ones (R0-R2 proven)

    // DMA staging geometry: wave w covers rows w*16..w*16+15 in two issues
    // of 8 rows; lane -> (row = r0 + (lane>>3), physical chunk = lane&7).
    // Global source fetches logical chunk pc ^ (row&7) = pc ^ lrow.
    const int lrow = lane >> 3;
    const int pc = lane & 7;
    const int swz = (pc ^ lrow) * 8;      // shorts
    const int lb = w * 1024;              // wave's LDS base (shorts)
    const ushort_t* kg = Kb + (size_t)h * 64 +
                         ((size_t)z * KEYS + w * 16 + lrow) * PROJ + swz;
    const ushort_t* vg = Vt + ((size_t)h * 64 + w * 16 + lrow) * N_TOK +
                         (size_t)z * KEYS + swz;

    const int xm = l31 & 7;               // fragment-read swizzle mask

    // prologue: stage tile 0 -> buf 0 (drained by first loop barrier)
    gld_lds16(kg,             &Ks[lb]);
    gld_lds16(kg + 8 * PROJ,  &Ks[lb + 512]);
    gld_lds16(vg,             &Vs[lb]);
    gld_lds16(vg + 8 * N_TOK, &Vs[lb + 512]);
    kg += 64 * PROJ;
    vg += 64;

    for (int lt = 0; lt < TILES; ++lt) {
        const int bo = (lt & 1) << 12;    // read-buffer offset (shorts)
        __syncthreads();                  // vmcnt(0)+barrier: buf[lt&1] ready,
                                          // all waves done with buf[lt^1]
        if (lt + 1 < TILES) {             // DMA tile lt+1 into other buffer
            const int bw = ((lt + 1) & 1) << 12;
            gld_lds16(kg,             &Ks[bw + lb]);
            gld_lds16(kg + 8 * PROJ,  &Ks[bw + lb + 512]);
            gld_lds16(vg,             &Vs[bw + lb]);
            gld_lds16(vg + 8 * N_TOK, &Vs[bw + lb + 512]);
            kg += 64 * PROJ;
            vg += 64;
        }

        // ================= half A: keys 0-31 =================
        {
            f32x16 s0 = {};
            __builtin_amdgcn_s_setprio(1);
#pragma unroll
            for (int ks = 0; ks < 4; ++ks) {
                const int pos = ((ks * 2 + hf) ^ xm) * 8;
                bf16x8 ka = *(const bf16x8*)&Ks[bo + l31 * 64 + pos];
                s0 = __builtin_amdgcn_mfma_f32_32x32x16_bf16(ka, qb[ks], s0, 0, 0, 0);
            }
            __builtin_amdgcn_s_setprio(0);

            float p[16];
#pragma unroll
            for (int r = 0; r < 16; ++r) {
                p[r] = __builtin_amdgcn_rcpf(1.0f + __builtin_amdgcn_exp2f(s0[r]));
            }
            unsigned d00 = cvtpk_bf16(p[0],  p[1]);
            unsigned d01 = cvtpk_bf16(p[2],  p[3]);
            unsigned d10 = cvtpk_bf16(p[4],  p[5]);
            unsigned d11 = cvtpk_bf16(p[6],  p[7]);
            unsigned d20 = cvtpk_bf16(p[8],  p[9]);
            unsigned d21 = cvtpk_bf16(p[10], p[11]);
            unsigned d30 = cvtpk_bf16(p[12], p[13]);
            unsigned d31 = cvtpk_bf16(p[14], p[15]);
            PLSWAP(d00, d10);
            PLSWAP(d01, d11);
            PLSWAP(d20, d30);
            PLSWAP(d21, d31);
            union { unsigned u[4]; bf16x8 v; } A0, A1;
            A0.u[0] = d00; A0.u[1] = d01; A0.u[2] = d10; A0.u[3] = d11;
            A1.u[0] = d20; A1.u[1] = d21; A1.u[2] = d30; A1.u[3] = d31;

            __builtin_amdgcn_s_setprio(1);
            {
                const int pos = ((0 + hf) ^ xm) * 8;          // ks=0
                bf16x8 vb0 = *(const bf16x8*)&Vs[bo + l31 * 64 + pos];
                o0 = __builtin_amdgcn_mfma_f32_32x32x16_bf16(A0.v, vb0, o0, 0, 0, 0);
                bf16x8 vb1 = *(const bf16x8*)&Vs[bo + (32 + l31) * 64 + pos];
                o1 = __builtin_amdgcn_mfma_f32_32x32x16_bf16(A0.v, vb1, o1, 0, 0, 0);
            }
            dacc = __builtin_amdgcn_mfma_f32_32x32x16_bf16(A0.v, onesv, dacc, 0, 0, 0);
            {
                const int pos = ((2 + hf) ^ xm) * 8;          // ks=1
                bf16x8 vb0 = *(const bf16x8*)&Vs[bo + l31 * 64 + pos];
                o0 = __builtin_amdgcn_mfma_f32_32x32x16_bf16(A1.v, vb0, o0, 0, 0, 0);
                bf16x8 vb1 = *(const bf16x8*)&Vs[bo + (32 + l31) * 64 + pos];
                o1 = __builtin_amdgcn_mfma_f32_32x32x16_bf16(A1.v, vb1, o1, 0, 0, 0);
            }
            dacc = __builtin_amdgcn_mfma_f32_32x32x16_bf16(A1.v, onesv, dacc, 0, 0, 0);
            __builtin_amdgcn_s_setprio(0);
        }

        // ================= half B: keys 32-63 =================
        {
            f32x16 s1 = {};
            __builtin_amdgcn_s_setprio(1);
#pragma unroll
            for (int ks = 0; ks < 4; ++ks) {
                const int pos = ((ks * 2 + hf) ^ xm) * 8;
                bf16x8 ka = *(const bf16x8*)&Ks[bo + (32 + l31) * 64 + pos];
                s1 = __builtin_amdgcn_mfma_f32_32x32x16_bf16(ka, qb[ks], s1, 0, 0, 0);
            }
            __builtin_amdgcn_s_setprio(0);

            float p[16];
#pragma unroll
            for (int r = 0; r < 16; ++r) {
                p[r] = __builtin_amdgcn_rcpf(1.0f + __builtin_amdgcn_exp2f(s1[r]));
            }
            unsigned e00 = cvtpk_bf16(p[0],  p[1]);
            unsigned e01 = cvtpk_bf16(p[2],  p[3]);
            unsigned e10 = cvtpk_bf16(p[4],  p[5]);
            unsigned e11 = cvtpk_bf16(p[6],  p[7]);
            unsigned e20 = cvtpk_bf16(p[8],  p[9]);
            unsigned e21 = cvtpk_bf16(p[10], p[11]);
            unsigned e30 = cvtpk_bf16(p[12], p[13]);
            unsigned e31 = cvtpk_bf16(p[14], p[15]);
            PLSWAP(e00, e10);
            PLSWAP(e01, e11);
            PLSWAP(e20, e30);
            PLSWAP(e21, e31);
            union { unsigned u[4]; bf16x8 v; } A2, A3;
            A2.u[0] = e00; A2.u[1] = e01; A2.u[2] = e10; A2.u[3] = e11;
            A3.u[0] = e20; A3.u[1] = e21; A3.u[2] = e30; A3.u[3] = e31;

            __builtin_amdgcn_s_setprio(1);
            {
                const int pos = ((4 + hf) ^ xm) * 8;          // ks=2
                bf16x8 vb0 = *(const bf16x8*)&Vs[bo + l31 * 64 + pos];
                o0 = __builtin_amdgcn_mfma_f32_32x32x16_bf16(A2.v, vb0, o0, 0, 0, 0);
                bf16x8 vb1 = *(const bf16x8*)&Vs[bo + (32 + l31) * 64 + pos];
                o1 = __builtin_amdgcn_mfma_f32_32x32x16_bf16(A2.v, vb1, o1, 0, 0, 0);
            }
            dacc = __builtin_amdgcn_mfma_f32_32x32x16_bf16(A2.v, onesv, dacc, 0, 0, 0);
            {
                const int pos = ((6 + hf) ^ xm) * 8;          // ks=3
                bf16x8 vb0 = *(const bf16x8*)&Vs[bo + l31 * 64 + pos];
                o0 = __builtin_amdgcn_mfma_f32_32x32x16_bf16(A3.v, vb0, o0, 0, 0, 0);
                bf16x8 vb1 = *(const bf16x8*)&Vs[bo + (32 + l31) * 64 + pos];
                o1 = __builtin_amdgcn_mfma_f32_32x32x16_bf16(A3.v, vb1, o1, 0, 0, 0);
            }
            dacc = __builtin_amdgcn_mfma_f32_32x32x16_bf16(A3.v, onesv, dacc, 0, 0, 0);
            __builtin_amdgcn_s_setprio(0);
        }
    }

    // epilogue: unnormalized numerator (f16).  q-row = (r&3)+8*(r>>2)+4*hf
#pragma unroll
    for (int rq = 0; rq < 4; ++rq) {
#pragma unroll
        for (int j = 0; j < 4; ++j) {
            const int q = n0 + w * 32 + rq * 8 + hf * 4 + j;
            f16_t* np_ = &NUM[((size_t)z * N_TOK + q) * PROJ + h * 64 + l31];
            np_[0]  = (f16_t)o0[rq * 4 + j];
            np_[32] = (f16_t)o1[rq * 4 + j];
        }
    }
    // DEN from dacc: D[q][c] = sum_k P[q][k]*1, identical across cols c.
    // Lane col l31==0 of each half writes its 16 q-rows.
    if (l31 == 0) {
#pragma unroll
        for (int r = 0; r < 16; ++r) {
            const int q = n0 + w * 32 + (r & 3) + 8 * (r >> 2) + 4 * hf;
            DEN[((size_t)z * N_TOK + q) * HEADS + h] = dacc[r];
        }
    }
}

// ---------------------------------------------------------------------------
// Kernel 3 (R14): out[n][d] = (1/8) * sum_h (sum_z NUM_z)/(sum_z DEN_z)
// Vectorized: each thread handles 2 consecutive d via u32 (f16x2) NUM loads
// and one float2 out store (G13).  grid N*32/256 = 512 blocks.
// ---------------------------------------------------------------------------
template<int ZS>
__global__ __launch_bounds__(256) void reduce_kernel(
    const f16_t* __restrict__ NUM, const float* __restrict__ DEN,
    float* __restrict__ out)
{
    const int g = blockIdx.x * 256 + threadIdx.x;   // covers N*32
    const int n = g >> 5;
    const int d2 = (g & 31) * 2;
    float a0 = 0.0f, a1 = 0.0f;
#pragma unroll
    for (int hh = 0; hh < HEADS; ++hh) {
        float n0 = 0.0f, n1 = 0.0f, dd = 0.0f;
#pragma unroll
        for (int zz = 0; zz < ZS; ++zz) {
            union { unsigned u; f16_t h[2]; } cv;
            cv.u = *(const unsigned*)&NUM[((size_t)zz * N_TOK + n) * PROJ + hh * 64 + d2];
            n0 += (float)cv.h[0];
            n1 += (float)cv.h[1];
            dd += DEN[((size_t)zz * N_TOK + n) * HEADS + hh];
        }
        a0 += n0 / dd;
        a1 += n1 / dd;
    }
    float2 res;
    res.x = a0 * 0.125f;
    res.y = a1 * 0.125f;
    *(float2*)&out[(size_t)n * 64 + d2] = res;
}

extern "C" void kernel_launch(void* const* d_in, const int* in_sizes, int n_in,
                              void* d_out, int out_size, void* d_ws, size_t ws_size,
                              hipStream_t stream) {
    (void)in_sizes; (void)n_in; (void)out_size;
    const float* X  = (const float*)d_in[0];
    const float* Wq = (const float*)d_in[1];
    const float* bq = (const float*)d_in[2];
    const float* Wk = (const float*)d_in[3];
    const float* bk = (const float*)d_in[4];
    const float* Wv = (const float*)d_in[5];
    const float* bv = (const float*)d_in[6];
    float* out = (float*)d_out;

    // ws need at ZS=4: 16.78M (NUM f16) + 0.52M (DEN) + 12.58M (Qb/Kb/Vt)
    //                + 2.10M (Xa) + 0.79M (Wp) = 32.8 MB.  Fallback ZS=2.
    const size_t NEED4 =
        (size_t)4 * N_TOK * PROJ * 2 + (size_t)4 * N_TOK * HEADS * 4 +
        (size_t)3 * N_TOK * PROJ * 2 + (size_t)N_TOK * IN_CH * 2 +
        (size_t)3 * PROJ * IN_CH * 2;
    const int ZS = (ws_size >= NEED4) ? 4 : 2;

    f16_t* NUM = (f16_t*)d_ws;                              // [ZS][N][PROJ] f16
    float* DEN = (float*)(NUM + (size_t)ZS * N_TOK * PROJ); // [ZS][N][HEADS] f32
    ushort_t* Qb = (ushort_t*)(DEN + (size_t)ZS * N_TOK * HEADS);
    ushort_t* Kb = Qb + (size_t)N_TOK * PROJ;
    ushort_t* Vt = Kb + (size_t)N_TOK * PROJ;               // [H][64][N]
    ushort_t* Xa = Vt + (size_t)N_TOK * PROJ;               // frag-packed X
    ushort_t* Wp = Xa + (size_t)N_TOK * IN_CH;              // frag-packed W x3

    cast_pack_kernel<<<dim3(704), 256, 0, stream>>>(X, Wq, Wk, Wv, Xa, Wp);
    proj_mfma_kernel<<<dim3(PROJ / 64, N_TOK / 64, 3), 256, 0, stream>>>(
        Xa, Wp, bq, bk, bv, Qb, Kb, Vt);
    if (ZS == 4) {
        attn_kernel<4><<<dim3(N_TOK / 128, HEADS, 4), 256, 0, stream>>>(
            Qb, Kb, Vt, NUM, DEN);
        reduce_kernel<4><<<dim3(N_TOK * 32 / 256), 256, 0, stream>>>(
            NUM, DEN, out);
    } else {
        attn_kernel<2><<<dim3(N_TOK / 128, HEADS, 2), 256, 0, stream>>>(
            Qb, Kb, Vt, NUM, DEN);
        reduce_kernel<2><<<dim3(N_TOK * 32 / 256), 256, 0, stream>>>(
            NUM, DEN, out);
    }
}

// Round 16
// 129.216 us; speedup vs baseline: 1.1144x; 1.0321x over previous
//
#include <hip/hip_runtime.h>
#include <hip/hip_bf16.h>
#include <math.h>

#define N_TOK 4096
#define IN_CH 256
#define OUT_CH 64
#define HEADS 8
#define PROJ (OUT_CH * HEADS) /* 512 */
#define NLOG2E -1.44269504088896340736f

typedef float f32x4 __attribute__((ext_vector_type(4)));
typedef float f32x16 __attribute__((ext_vector_type(16)));
typedef __bf16 bf16x8 __attribute__((ext_vector_type(8)));
typedef unsigned short ushort_t;
typedef _Float16 f16_t;

__device__ inline ushort_t bf16rne(float x) {
    unsigned u = __float_as_uint(x);
    unsigned r = (u + 0x7FFFu + ((u >> 16) & 1u)) >> 16;
    return (ushort_t)r;
}

// packed f32->bf16x2 convert (RNE): D[15:0]=bf16(lo), D[31:16]=bf16(hi).
__device__ inline unsigned cvtpk_bf16(float lo, float hi) {
    unsigned d;
    asm("v_cvt_pk_bf16_f32 %0, %1, %2" : "=v"(d) : "v"(lo), "v"(hi));
    return d;
}
// v_permlane32_swap_b32 VDST, VSRC (R5-verified semantics):
// After PLSWAP(x, y):  x = {lo: own x,      hi: partner y}
//                      y = {lo: partner x,  hi: own y}
#define PLSWAP(x, y) asm("v_permlane32_swap_b32 %0, %1" : "+v"(x), "+v"(y))

// NOTE: SIGPK fused-softmax macro remains RETIRED (R8/R9 bit-identical
// miscompile at absmax 860.033; R10 isolated it).
// NOTE: R13 cast-into-proj fusion RETIRED (strided f32 reads, +16 us).
// NOTE: R14 vectorized reduce UNPROVEN (confounded with a +2% noise run).
// R16 == R12-measured champion (128.3 us); R15 was an infra failure.

// async global->LDS DMA, 16B per lane.  LDS dest = wave-uniform base +
// lane*16; swizzle achieved by pre-swizzling the per-lane GLOBAL address.
__device__ inline void gld_lds16(const ushort_t* g, ushort_t* l) {
    __builtin_amdgcn_global_load_lds(
        (const __attribute__((address_space(1))) unsigned int*)g,
        (__attribute__((address_space(3))) unsigned int*)l,
        16, 0, 0);
}

// ---------------------------------------------------------------------------
// Kernel 0: cast X / Wq / Wk / Wv to bf16 AND pre-permute into MFMA fragment
// order:  flat index (((g*8 + k8)*4 + quad)*16 + t)*8  (g = 16-row group).
// Wq additionally scaled by -log2(e) so sigmoid = rcp(1 + exp2(t)).
// ---------------------------------------------------------------------------
__global__ __launch_bounds__(256) void cast_pack_kernel(
    const float* __restrict__ X,
    const float* __restrict__ Wq, const float* __restrict__ Wk,
    const float* __restrict__ Wv,
    ushort_t* __restrict__ Xa, ushort_t* __restrict__ Wp)
{
    const int i = blockIdx.x * 256 + threadIdx.x;
    const float* src;
    ushort_t* dst;
    float scale = 1.0f;
    if (i < 131072) {                       // X part: N*IN_CH/8 packs
        const int t = i & 15, quad = (i >> 4) & 3, k8 = (i >> 6) & 7, g = i >> 9;
        src = X + (size_t)(g * 16 + t) * IN_CH + k8 * 32 + quad * 8;
        dst = Xa + (size_t)i * 8;
    } else {                                // W part: 3*PROJ*IN_CH/8 packs
        const int j = i - 131072;
        const int z = j >> 14;
        const int r = j & 16383;
        const int cl = r & 15, quad = (r >> 4) & 3, k8 = (r >> 6) & 7, gc = r >> 9;
        const float* W = (z == 0) ? Wq : (z == 1) ? Wk : Wv;
        src = W + (size_t)(gc * 16 + cl) * IN_CH + k8 * 32 + quad * 8;
        dst = Wp + (size_t)z * 131072 * 8 + (size_t)r * 8;
        if (z == 0) scale = NLOG2E;
    }
    float4 a = *(const float4*)src;
    float4 b = *(const float4*)(src + 4);
    ushort_t pk[8];
    pk[0] = bf16rne(a.x * scale); pk[1] = bf16rne(a.y * scale);
    pk[2] = bf16rne(a.z * scale); pk[3] = bf16rne(a.w * scale);
    pk[4] = bf16rne(b.x * scale); pk[5] = bf16rne(b.y * scale);
    pk[6] = bf16rne(b.z * scale); pk[7] = bf16rne(b.w * scale);
    *(uint4*)dst = *(uint4*)pk;
}

// ---------------------------------------------------------------------------
// Kernel 1 (R10-proven DMA version): Q/K/V projections via bf16 MFMA.
// grid (PROJ/64, N/64, 3), block 256 (4 waves).  Wave w: 16 tokens x 64 cols.
// W staged through LDS via global_load_lds DMA, double-buffered per
// k8-slice.  Global traffic/block: 160 -> 64 KB; b-operand L2 -> LDS.
// Epilogue: LDS transpose so all global stores are uint4.
//   z=0 -> Qb [N][PROJ] (pre-scaled by -log2e), z=1 -> Kb, z=2 -> Vt [H][64][N]
// ---------------------------------------------------------------------------
__global__ __launch_bounds__(256) void proj_mfma_kernel(
    const ushort_t* __restrict__ Xa, const ushort_t* __restrict__ Wp,
    const float* __restrict__ bq, const float* __restrict__ bk,
    const float* __restrict__ bv,
    ushort_t* __restrict__ Qb, ushort_t* __restrict__ Kb,
    ushort_t* __restrict__ Vt)
{
    const int z = blockIdx.z;
    const float* bias = (z == 0) ? bq : (z == 1) ? bk : bv;
    const float bscale = (z == 0) ? NLOG2E : 1.0f;
    const int c0 = blockIdx.x * 64;
    const int n0 = blockIdx.y * 64;

    const int tid = threadIdx.x;
    const int w = tid >> 6;
    const int lane = tid & 63;
    const int l15 = lane & 15;
    const int quad = lane >> 4;

    __shared__ ushort_t Ws[2 * 2048];  // [buf][colgroup f][lane*8] (8 KB)
    __shared__ ushort_t Es[64 * 68];   // epilogue transpose tile (8.7 KB)

    // X fragments: per-wave private, straight from global (L2-hot, read once)
    const ushort_t* xa = Xa + (size_t)(blockIdx.y * 4 + w) * 4096 + lane * 8;
    // W DMA source: wave w stages col-group w's k8-slice
    const ushort_t* wsrc = Wp + (size_t)z * 131072 * 8 +
                           (size_t)(blockIdx.x * 4 + w) * 4096 + lane * 8;

    f32x4 acc[4] = {{0.f, 0.f, 0.f, 0.f}, {0.f, 0.f, 0.f, 0.f},
                    {0.f, 0.f, 0.f, 0.f}, {0.f, 0.f, 0.f, 0.f}};

    // prologue: stage k8=0 slice -> buf0
    gld_lds16(wsrc, &Ws[w * 512]);

#pragma unroll
    for (int k8 = 0; k8 < 8; ++k8) {
        const int bo = (k8 & 1) * 2048;
        __syncthreads();               // vmcnt(0)+barrier: buf[k8&1] ready,
                                       // all waves done with buf[k8^1]
        if (k8 < 7)
            gld_lds16(wsrc + (k8 + 1) * 512,
                      &Ws[((k8 + 1) & 1) * 2048 + w * 512]);
        bf16x8 a = *(const bf16x8*)(xa + k8 * 512);
#pragma unroll
        for (int f = 0; f < 4; ++f) {
            bf16x8 b = *(const bf16x8*)&Ws[bo + f * 512 + lane * 8];
            acc[f] = __builtin_amdgcn_mfma_f32_16x16x32_bf16(a, b, acc[f], 0, 0, 0);
        }
    }

    // bias + bf16 round into LDS (layout depends on z), then coalesced store
    if (z < 2) {
        // Es[tok][c]
#pragma unroll
        for (int f = 0; f < 4; ++f) {
            const float bb = bias[c0 + f * 16 + l15] * bscale;
#pragma unroll
            for (int r = 0; r < 4; ++r)
                Es[(w * 16 + quad * 4 + r) * 68 + f * 16 + l15] = bf16rne(acc[f][r] + bb);
        }
    } else {
        // Es[c][tok]
#pragma unroll
        for (int f = 0; f < 4; ++f) {
            const float bb = bias[c0 + f * 16 + l15];
#pragma unroll
            for (int r = 0; r < 4; ++r)
                Es[(f * 16 + l15) * 68 + w * 16 + quad * 4 + r] = bf16rne(acc[f][r] + bb);
        }
    }
    __syncthreads();

    const int erow = tid >> 2;            // 0..63
    const int ecol = (tid & 3) * 16;      // 0,16,32,48 (+8 second store)
    uint4 pk0 = *(uint4*)&Es[erow * 68 + ecol];
    uint4 pk1 = *(uint4*)&Es[erow * 68 + ecol + 8];
    if (z < 2) {
        ushort_t* out = z ? Kb : Qb;
        ushort_t* p = &out[(size_t)(n0 + erow) * PROJ + c0 + ecol];
        *(uint4*)p = pk0;
        *(uint4*)(p + 8) = pk1;
    } else {
        ushort_t* p = &Vt[(size_t)(c0 + erow) * N_TOK + n0 + ecol];
        *(uint4*)p = pk0;
        *(uint4*)(p + 8) = pk1;
    }
}

// ---------------------------------------------------------------------------
// Kernel 2 (R12-proven, byte-identical): fused sigmoid attention,
// bf16 MFMA 32x32x16.  global_load_lds K/V staging, double-buffered, one
// barrier/tile; Ps-LDS-free softmax (T12 cvt_pk + permlane32_swap); 32-key
// half-pipelines with p[16] softmax; DEN on the MFMA pipe via ones-B
// fragment (dacc in AGPRs); NUM stored f16.
// block 256 (4 waves x 32 q), grid (32, 8, ZS=4) = 1024 = 4/CU.
// ---------------------------------------------------------------------------
template<int ZS>
__global__ __launch_bounds__(256, 4) void attn_kernel(
    const ushort_t* __restrict__ Qb, const ushort_t* __restrict__ Kb,
    const ushort_t* __restrict__ Vt,
    f16_t* __restrict__ NUM, float* __restrict__ DEN)
{
    constexpr int KEYS = N_TOK / ZS;      // keys per block
    constexpr int TILES = KEYS / 64;      // 64-key tiles per block

    const int h = blockIdx.y;
    const int z = blockIdx.z;
    const int n0 = blockIdx.x * 128;
    const int tid = threadIdx.x;
    const int w = tid >> 6;               // 0..3, wave owns queries w*32..+31
    const int lane = tid & 63;
    const int l31 = lane & 31;
    const int hf = lane >> 5;             // half-wave: k-chunk select

    __shared__ ushort_t Ks[2 * 64 * 64];  // [buf][key][d], xor-swizzled chunks
    __shared__ ushort_t Vs[2 * 64 * 64];  // [buf][d][key], xor-swizzled chunks

    // Q B-fragments, register-resident (pre-scaled by -log2e).
    bf16x8 qb[4];
    {
        const ushort_t* base = Qb + (size_t)(n0 + w * 32 + l31) * PROJ + h * 64 + hf * 8;
        qb[0] = *(const bf16x8*)(base);
        qb[1] = *(const bf16x8*)(base + 16);
        qb[2] = *(const bf16x8*)(base + 32);
        qb[3] = *(const bf16x8*)(base + 48);
    }

    bf16x8 onesv;
#pragma unroll
    for (int j = 0; j < 8; ++j) onesv[j] = (__bf16)1.0f;

    f32x16 o0 = {};                       // O[q][d: 0..31]
    f32x16 o1 = {};                       // O[q][d: 32..63]
    f32x16 dacc = {};                     // DEN via MFMA-ones (R0-R2 proven)

    // DMA staging geometry: wave w covers rows w*16..w*16+15 in two issues
    // of 8 rows; lane -> (row = r0 + (lane>>3), physical chunk = lane&7).
    // Global source fetches logical chunk pc ^ (row&7) = pc ^ lrow.
    const int lrow = lane >> 3;
    const int pc = lane & 7;
    const int swz = (pc ^ lrow) * 8;      // shorts
    const int lb = w * 1024;              // wave's LDS base (shorts)
    const ushort_t* kg = Kb + (size_t)h * 64 +
                         ((size_t)z * KEYS + w * 16 + lrow) * PROJ + swz;
    const ushort_t* vg = Vt + ((size_t)h * 64 + w * 16 + lrow) * N_TOK +
                         (size_t)z * KEYS + swz;

    const int xm = l31 & 7;               // fragment-read swizzle mask

    // prologue: stage tile 0 -> buf 0 (drained by first loop barrier)
    gld_lds16(kg,             &Ks[lb]);
    gld_lds16(kg + 8 * PROJ,  &Ks[lb + 512]);
    gld_lds16(vg,             &Vs[lb]);
    gld_lds16(vg + 8 * N_TOK, &Vs[lb + 512]);
    kg += 64 * PROJ;
    vg += 64;

    for (int lt = 0; lt < TILES; ++lt) {
        const int bo = (lt & 1) << 12;    // read-buffer offset (shorts)
        __syncthreads();                  // vmcnt(0)+barrier: buf[lt&1] ready,
                                          // all waves done with buf[lt^1]
        if (lt + 1 < TILES) {             // DMA tile lt+1 into other buffer
            const int bw = ((lt + 1) & 1) << 12;
            gld_lds16(kg,             &Ks[bw + lb]);
            gld_lds16(kg + 8 * PROJ,  &Ks[bw + lb + 512]);
            gld_lds16(vg,             &Vs[bw + lb]);
            gld_lds16(vg + 8 * N_TOK, &Vs[bw + lb + 512]);
            kg += 64 * PROJ;
            vg += 64;
        }

        // ================= half A: keys 0-31 =================
        {
            f32x16 s0 = {};
            __builtin_amdgcn_s_setprio(1);
#pragma unroll
            for (int ks = 0; ks < 4; ++ks) {
                const int pos = ((ks * 2 + hf) ^ xm) * 8;
                bf16x8 ka = *(const bf16x8*)&Ks[bo + l31 * 64 + pos];
                s0 = __builtin_amdgcn_mfma_f32_32x32x16_bf16(ka, qb[ks], s0, 0, 0, 0);
            }
            __builtin_amdgcn_s_setprio(0);

            float p[16];
#pragma unroll
            for (int r = 0; r < 16; ++r) {
                p[r] = __builtin_amdgcn_rcpf(1.0f + __builtin_amdgcn_exp2f(s0[r]));
            }
            unsigned d00 = cvtpk_bf16(p[0],  p[1]);
            unsigned d01 = cvtpk_bf16(p[2],  p[3]);
            unsigned d10 = cvtpk_bf16(p[4],  p[5]);
            unsigned d11 = cvtpk_bf16(p[6],  p[7]);
            unsigned d20 = cvtpk_bf16(p[8],  p[9]);
            unsigned d21 = cvtpk_bf16(p[10], p[11]);
            unsigned d30 = cvtpk_bf16(p[12], p[13]);
            unsigned d31 = cvtpk_bf16(p[14], p[15]);
            PLSWAP(d00, d10);
            PLSWAP(d01, d11);
            PLSWAP(d20, d30);
            PLSWAP(d21, d31);
            union { unsigned u[4]; bf16x8 v; } A0, A1;
            A0.u[0] = d00; A0.u[1] = d01; A0.u[2] = d10; A0.u[3] = d11;
            A1.u[0] = d20; A1.u[1] = d21; A1.u[2] = d30; A1.u[3] = d31;

            __builtin_amdgcn_s_setprio(1);
            {
                const int pos = ((0 + hf) ^ xm) * 8;          // ks=0
                bf16x8 vb0 = *(const bf16x8*)&Vs[bo + l31 * 64 + pos];
                o0 = __builtin_amdgcn_mfma_f32_32x32x16_bf16(A0.v, vb0, o0, 0, 0, 0);
                bf16x8 vb1 = *(const bf16x8*)&Vs[bo + (32 + l31) * 64 + pos];
                o1 = __builtin_amdgcn_mfma_f32_32x32x16_bf16(A0.v, vb1, o1, 0, 0, 0);
            }
            dacc = __builtin_amdgcn_mfma_f32_32x32x16_bf16(A0.v, onesv, dacc, 0, 0, 0);
            {
                const int pos = ((2 + hf) ^ xm) * 8;          // ks=1
                bf16x8 vb0 = *(const bf16x8*)&Vs[bo + l31 * 64 + pos];
                o0 = __builtin_amdgcn_mfma_f32_32x32x16_bf16(A1.v, vb0, o0, 0, 0, 0);
                bf16x8 vb1 = *(const bf16x8*)&Vs[bo + (32 + l31) * 64 + pos];
                o1 = __builtin_amdgcn_mfma_f32_32x32x16_bf16(A1.v, vb1, o1, 0, 0, 0);
            }
            dacc = __builtin_amdgcn_mfma_f32_32x32x16_bf16(A1.v, onesv, dacc, 0, 0, 0);
            __builtin_amdgcn_s_setprio(0);
        }

        // ================= half B: keys 32-63 =================
        {
            f32x16 s1 = {};
            __builtin_amdgcn_s_setprio(1);
#pragma unroll
            for (int ks = 0; ks < 4; ++ks) {
                const int pos = ((ks * 2 + hf) ^ xm) * 8;
                bf16x8 ka = *(const bf16x8*)&Ks[bo + (32 + l31) * 64 + pos];
                s1 = __builtin_amdgcn_mfma_f32_32x32x16_bf16(ka, qb[ks], s1, 0, 0, 0);
            }
            __builtin_amdgcn_s_setprio(0);

            float p[16];
#pragma unroll
            for (int r = 0; r < 16; ++r) {
                p[r] = __builtin_amdgcn_rcpf(1.0f + __builtin_amdgcn_exp2f(s1[r]));
            }
            unsigned e00 = cvtpk_bf16(p[0],  p[1]);
            unsigned e01 = cvtpk_bf16(p[2],  p[3]);
            unsigned e10 = cvtpk_bf16(p[4],  p[5]);
            unsigned e11 = cvtpk_bf16(p[6],  p[7]);
            unsigned e20 = cvtpk_bf16(p[8],  p[9]);
            unsigned e21 = cvtpk_bf16(p[10], p[11]);
            unsigned e30 = cvtpk_bf16(p[12], p[13]);
            unsigned e31 = cvtpk_bf16(p[14], p[15]);
            PLSWAP(e00, e10);
            PLSWAP(e01, e11);
            PLSWAP(e20, e30);
            PLSWAP(e21, e31);
            union { unsigned u[4]; bf16x8 v; } A2, A3;
            A2.u[0] = e00; A2.u[1] = e01; A2.u[2] = e10; A2.u[3] = e11;
            A3.u[0] = e20; A3.u[1] = e21; A3.u[2] = e30; A3.u[3] = e31;

            __builtin_amdgcn_s_setprio(1);
            {
                const int pos = ((4 + hf) ^ xm) * 8;          // ks=2
                bf16x8 vb0 = *(const bf16x8*)&Vs[bo + l31 * 64 + pos];
                o0 = __builtin_amdgcn_mfma_f32_32x32x16_bf16(A2.v, vb0, o0, 0, 0, 0);
                bf16x8 vb1 = *(const bf16x8*)&Vs[bo + (32 + l31) * 64 + pos];
                o1 = __builtin_amdgcn_mfma_f32_32x32x16_bf16(A2.v, vb1, o1, 0, 0, 0);
            }
            dacc = __builtin_amdgcn_mfma_f32_32x32x16_bf16(A2.v, onesv, dacc, 0, 0, 0);
            {
                const int pos = ((6 + hf) ^ xm) * 8;          // ks=3
                bf16x8 vb0 = *(const bf16x8*)&Vs[bo + l31 * 64 + pos];
                o0 = __builtin_amdgcn_mfma_f32_32x32x16_bf16(A3.v, vb0, o0, 0, 0, 0);
                bf16x8 vb1 = *(const bf16x8*)&Vs[bo + (32 + l31) * 64 + pos];
                o1 = __builtin_amdgcn_mfma_f32_32x32x16_bf16(A3.v, vb1, o1, 0, 0, 0);
            }
            dacc = __builtin_amdgcn_mfma_f32_32x32x16_bf16(A3.v, onesv, dacc, 0, 0, 0);
            __builtin_amdgcn_s_setprio(0);
        }
    }

    // epilogue: unnormalized numerator (f16).  q-row = (r&3)+8*(r>>2)+4*hf
#pragma unroll
    for (int rq = 0; rq < 4; ++rq) {
#pragma unroll
        for (int j = 0; j < 4; ++j) {
            const int q = n0 + w * 32 + rq * 8 + hf * 4 + j;
            f16_t* np_ = &NUM[((size_t)z * N_TOK + q) * PROJ + h * 64 + l31];
            np_[0]  = (f16_t)o0[rq * 4 + j];
            np_[32] = (f16_t)o1[rq * 4 + j];
        }
    }
    // DEN from dacc: D[q][c] = sum_k P[q][k]*1, identical across cols c.
    // Lane col l31==0 of each half writes its 16 q-rows.
    if (l31 == 0) {
#pragma unroll
        for (int r = 0; r < 16; ++r) {
            const int q = n0 + w * 32 + (r & 3) + 8 * (r >> 2) + 4 * hf;
            DEN[((size_t)z * N_TOK + q) * HEADS + h] = dacc[r];
        }
    }
}

// ---------------------------------------------------------------------------
// Kernel 3: out[n][d] = (1/8) * sum_h (sum_z NUM_z)/(sum_z DEN_z)
// NUM is f16; DEN stays f32.  (R12-measured form.)
// ---------------------------------------------------------------------------
template<int ZS>
__global__ __launch_bounds__(256) void reduce_kernel(
    const f16_t* __restrict__ NUM, const float* __restrict__ DEN,
    float* __restrict__ out)
{
    const int g = blockIdx.x * 256 + threadIdx.x;
    const int n = g >> 6;
    const int d = g & 63;
    float acc = 0.0f;
#pragma unroll
    for (int hh = 0; hh < HEADS; ++hh) {
        float num = 0.0f, dd = 0.0f;
#pragma unroll
        for (int zz = 0; zz < ZS; ++zz) {
            num += (float)NUM[((size_t)zz * N_TOK + n) * PROJ + hh * 64 + d];
            dd  += DEN[((size_t)zz * N_TOK + n) * HEADS + hh];
        }
        acc += num / dd;
    }
    out[g] = acc * 0.125f;
}

extern "C" void kernel_launch(void* const* d_in, const int* in_sizes, int n_in,
                              void* d_out, int out_size, void* d_ws, size_t ws_size,
                              hipStream_t stream) {
    (void)in_sizes; (void)n_in; (void)out_size;
    const float* X  = (const float*)d_in[0];
    const float* Wq = (const float*)d_in[1];
    const float* bq = (const float*)d_in[2];
    const float* Wk = (const float*)d_in[3];
    const float* bk = (const float*)d_in[4];
    const float* Wv = (const float*)d_in[5];
    const float* bv = (const float*)d_in[6];
    float* out = (float*)d_out;

    // ws need at ZS=4: 16.78M (NUM f16) + 0.52M (DEN) + 12.58M (Qb/Kb/Vt)
    //                + 2.10M (Xa) + 0.79M (Wp) = 32.8 MB.  Fallback ZS=2.
    const size_t NEED4 =
        (size_t)4 * N_TOK * PROJ * 2 + (size_t)4 * N_TOK * HEADS * 4 +
        (size_t)3 * N_TOK * PROJ * 2 + (size_t)N_TOK * IN_CH * 2 +
        (size_t)3 * PROJ * IN_CH * 2;
    const int ZS = (ws_size >= NEED4) ? 4 : 2;

    f16_t* NUM = (f16_t*)d_ws;                              // [ZS][N][PROJ] f16
    float* DEN = (float*)(NUM + (size_t)ZS * N_TOK * PROJ); // [ZS][N][HEADS] f32
    ushort_t* Qb = (ushort_t*)(DEN + (size_t)ZS * N_TOK * HEADS);
    ushort_t* Kb = Qb + (size_t)N_TOK * PROJ;
    ushort_t* Vt = Kb + (size_t)N_TOK * PROJ;               // [H][64][N]
    ushort_t* Xa = Vt + (size_t)N_TOK * PROJ;               // frag-packed X
    ushort_t* Wp = Xa + (size_t)N_TOK * IN_CH;              // frag-packed W x3

    cast_pack_kernel<<<dim3(704), 256, 0, stream>>>(X, Wq, Wk, Wv, Xa, Wp);
    proj_mfma_kernel<<<dim3(PROJ / 64, N_TOK / 64, 3), 256, 0, stream>>>(
        Xa, Wp, bq, bk, bv, Qb, Kb, Vt);
    if (ZS == 4) {
        attn_kernel<4><<<dim3(N_TOK / 128, HEADS, 4), 256, 0, stream>>>(
            Qb, Kb, Vt, NUM, DEN);
        reduce_kernel<4><<<dim3(N_TOK * OUT_CH / 256), 256, 0, stream>>>(
            NUM, DEN, out);
    } else {
        attn_kernel<2><<<dim3(N_TOK / 128, HEADS, 2), 256, 0, stream>>>(
            Qb, Kb, Vt, NUM, DEN);
        reduce_kernel<2><<<dim3(N_TOK * OUT_CH / 256), 256, 0, stream>>>(
            NUM, DEN, out);
    }
}